// Round 4
// baseline (237.528 us; speedup 1.0000x reference)
//
#include <hip/hip_runtime.h>
#include <hip/hip_bf16.h>

#define MM 16384
#define NN 4096
#define KK 512

typedef __bf16 bf16x8 __attribute__((ext_vector_type(8)));
typedef float  f32x4  __attribute__((ext_vector_type(4)));

// ---------------------------------------------------------------------------
// prep_x: x_sq[row] = ||X[row]||^2 (f32), Xb = bf16(X), out[row] = alpha
// one wave per row, 4 rows per block
// ---------------------------------------------------------------------------
__global__ __launch_bounds__(256) void prep_x_kernel(
    const float* __restrict__ X, const float* __restrict__ alpha,
    __bf16* __restrict__ Xb, float* __restrict__ x_sq, float* __restrict__ out)
{
    int row  = blockIdx.x * 4 + (threadIdx.x >> 6);
    int lane = threadIdx.x & 63;
    const float4* src = (const float4*)(X + (size_t)row * KK) + lane * 2;
    float4 a = src[0];
    float4 b = src[1];
    float s = a.x*a.x + a.y*a.y + a.z*a.z + a.w*a.w
            + b.x*b.x + b.y*b.y + b.z*b.z + b.w*b.w;
    bf16x8 v;
    v[0]=(__bf16)a.x; v[1]=(__bf16)a.y; v[2]=(__bf16)a.z; v[3]=(__bf16)a.w;
    v[4]=(__bf16)b.x; v[5]=(__bf16)b.y; v[6]=(__bf16)b.z; v[7]=(__bf16)b.w;
    *(bf16x8*)(Xb + (size_t)row * KK + lane * 8) = v;
    #pragma unroll
    for (int o = 1; o < 64; o <<= 1) s += __shfl_xor(s, o);
    if (lane == 0) { x_sq[row] = s; out[row] = alpha[0]; }
}

// ---------------------------------------------------------------------------
// prep_z: transpose+convert Z [512][4096] f32 -> Zt [4096][512] bf16
// 64x64 tiles via LDS (both sides coalesced)
// ---------------------------------------------------------------------------
__global__ __launch_bounds__(256) void prep_z_kernel(
    const float* __restrict__ Z, __bf16* __restrict__ Zt)
{
    __shared__ float t[64][65];
    const int n0 = blockIdx.x * 64;   // 64 blocks
    const int k0 = blockIdx.y * 64;   // 8 blocks
    const int tid = threadIdx.x;
    const int j = tid & 63, i0 = tid >> 6;
    #pragma unroll
    for (int p = 0; p < 16; ++p) {
        int i = i0 * 16 + p;
        t[i][j] = Z[(size_t)(k0 + i) * NN + n0 + j];
    }
    __syncthreads();
    const int nl = tid >> 2, kc = tid & 3;
    bf16x8 v0, v1;
    #pragma unroll
    for (int e = 0; e < 8; ++e) v0[e] = (__bf16)t[kc * 16 + e][nl];
    #pragma unroll
    for (int e = 0; e < 8; ++e) v1[e] = (__bf16)t[kc * 16 + 8 + e][nl];
    __bf16* dst = Zt + (size_t)(n0 + nl) * KK + k0 + kc * 16;
    *(bf16x8*)(dst)     = v0;
    *(bf16x8*)(dst + 8) = v1;
}

// ---------------------------------------------------------------------------
// prep_zsq: z_sq[c] = sum_k Z[k][c]^2   (f32 source for accuracy)
// 64 cols per block, k split 4-ways across the block, LDS reduce
// ---------------------------------------------------------------------------
__global__ __launch_bounds__(256) void prep_zsq_kernel(
    const float* __restrict__ Z, float* __restrict__ z_sq)
{
    __shared__ float red[4][64];
    const int cl = threadIdx.x & 63;
    const int kq = threadIdx.x >> 6;
    const int c  = blockIdx.x * 64 + cl;
    float s = 0.0f;
    for (int k = kq * 128; k < kq * 128 + 128; ++k) {
        float v = Z[(size_t)k * NN + c];
        s += v * v;
    }
    red[kq][cl] = s;
    __syncthreads();
    if (kq == 0) z_sq[c] = red[0][cl] + red[1][cl] + red[2][cl] + red[3][cl];
}

// ---------------------------------------------------------------------------
// fused bf16 GEMM (128x128 tile, BK=64, 4 waves 2x2, 64x64/wave) + RBF epilogue
// global_load_lds width=16 with pre-swizzled global source, XOR-swizzled
// ds_read_b128 (byte ^= (row&7)<<4) -> conflict-free LDS reads
// ---------------------------------------------------------------------------
__global__ __launch_bounds__(256) void rbfn_kernel(
    const __bf16* __restrict__ Xb, const __bf16* __restrict__ Zt,
    const float* __restrict__ x_sq, const float* __restrict__ z_sq,
    const float* __restrict__ beta, const float* __restrict__ log_gamma,
    float* __restrict__ out)
{
    __shared__ __bf16 As[128 * 64];
    __shared__ __bf16 Bs[128 * 64];

    const int tid  = threadIdx.x;
    const int wid  = tid >> 6;
    const int lane = tid & 63;
    const int wr = wid >> 1, wc = wid & 1;
    const int row0 = blockIdx.x * 128;
    const int col0 = blockIdx.y * 128;

    // staging: lane's linear LDS offset is lane*16B within a 1KB chunk (8 rows).
    // pre-apply the read-side XOR swizzle to the *global* source (rule #21).
    const int srow = lane >> 3;                       // row within 8-row chunk
    const int scol = ((lane & 7) * 8) ^ (srow * 8);   // element col, swizzled

    f32x4 acc[4][4] = {};

    const __bf16* Abase = Xb + (size_t)row0 * KK + scol;
    const __bf16* Bbase = Zt + (size_t)col0 * KK + scol;

    for (int k0 = 0; k0 < KK; k0 += 64) {
        #pragma unroll
        for (int i = 0; i < 4; ++i) {
            const int chunk = wid * 4 + i;            // 16 chunks x 1KB = 16KB tile
            const int r = chunk * 8 + srow;
            __builtin_amdgcn_global_load_lds(
                (const __attribute__((address_space(1))) void*)(Abase + (size_t)r * KK + k0),
                (__attribute__((address_space(3))) void*)(As + chunk * 512),
                16, 0, 0);
            __builtin_amdgcn_global_load_lds(
                (const __attribute__((address_space(1))) void*)(Bbase + (size_t)r * KK + k0),
                (__attribute__((address_space(3))) void*)(Bs + chunk * 512),
                16, 0, 0);
        }
        __syncthreads();   // drains vmcnt before any wave reads LDS

        #pragma unroll
        for (int q = 0; q < 2; ++q) {                 // two K=32 sub-steps
            bf16x8 af[4], bfv[4];
            #pragma unroll
            for (int m = 0; m < 4; ++m) {
                const int r = wr * 64 + m * 16 + (lane & 15);
                const int off = (r * 128 + q * 64 + (lane >> 4) * 16) ^ ((r & 7) << 4);
                af[m] = *(const bf16x8*)((const char*)As + off);
            }
            #pragma unroll
            for (int n = 0; n < 4; ++n) {
                const int r = wc * 64 + n * 16 + (lane & 15);
                const int off = (r * 128 + q * 64 + (lane >> 4) * 16) ^ ((r & 7) << 4);
                bfv[n] = *(const bf16x8*)((const char*)Bs + off);
            }
            #pragma unroll
            for (int m = 0; m < 4; ++m)
                #pragma unroll
                for (int n = 0; n < 4; ++n)
                    acc[m][n] = __builtin_amdgcn_mfma_f32_16x16x32_bf16(
                        af[m], bfv[n], acc[m][n], 0, 0, 0);
        }
        __syncthreads();   // protect LDS from next iteration's staging
    }

    // ---- fused RBF epilogue ----------------------------------------------
    // A = exp(-gamma*D) = exp2(fma(2c, b, -c*(x_sq+z_sq))), c = gamma*log2(e)
    const float gamma = __expf(log_gamma[0]);
    const float c2    = gamma * 1.4426950408889634f;
    const float twoc2 = 2.0f * c2;

    float czn[4], bet[4];
    const int colb = col0 + wc * 64 + (lane & 15);
    #pragma unroll
    for (int n = 0; n < 4; ++n) {
        const int c = colb + n * 16;
        czn[n] = -c2 * z_sq[c];
        bet[n] = beta[c];
    }

    const int rowb = row0 + wr * 64 + (lane >> 4) * 4;
    #pragma unroll
    for (int m = 0; m < 4; ++m) {
        #pragma unroll
        for (int j = 0; j < 4; ++j) {
            const int r = rowb + m * 16 + j;
            const float cx = -c2 * x_sq[r];
            float p = 0.0f;
            #pragma unroll
            for (int n = 0; n < 4; ++n) {
                const float arg = fmaf(twoc2, acc[m][n][j], cx + czn[n]);
                p = fmaf(exp2f(arg), bet[n], p);
            }
            // reduce across the 16 lanes holding this row's 64 columns
            p += __shfl_xor(p, 1);
            p += __shfl_xor(p, 2);
            p += __shfl_xor(p, 4);
            p += __shfl_xor(p, 8);
            if ((lane & 15) == 0) atomicAdd(&out[r], p);
        }
    }
}

// ---------------------------------------------------------------------------
extern "C" void kernel_launch(void* const* d_in, const int* in_sizes, int n_in,
                              void* d_out, int out_size, void* d_ws, size_t ws_size,
                              hipStream_t stream) {
    const float* X         = (const float*)d_in[0];
    const float* alpha     = (const float*)d_in[1];
    const float* log_gamma = (const float*)d_in[2];
    const float* beta      = (const float*)d_in[3];
    const float* Z         = (const float*)d_in[4];

    char* ws = (char*)d_ws;
    __bf16* Xb   = (__bf16*)(ws);                       // 16384*512*2 = 16 MB
    __bf16* Zt   = (__bf16*)(ws + 16777216);            // 4096*512*2  =  4 MB
    float*  x_sq = (float*) (ws + 20971520);            // 64 KB
    float*  z_sq = (float*) (ws + 21037056);            // 16 KB
    float*  out  = (float*)d_out;

    prep_x_kernel  <<<4096, 256, 0, stream>>>(X, alpha, Xb, x_sq, out);
    prep_z_kernel  <<<dim3(64, 8), 256, 0, stream>>>(Z, Zt);
    prep_zsq_kernel<<<64, 256, 0, stream>>>(Z, z_sq);
    rbfn_kernel    <<<dim3(128, 32), 256, 0, stream>>>(Xb, Zt, x_sq, z_sq, beta, log_gamma, out);
}

// Round 7
// 220.808 us; speedup vs baseline: 1.0757x; 1.0757x over previous
//
#include <hip/hip_runtime.h>
#include <hip/hip_bf16.h>

#define MM 16384
#define NN 4096
#define KK 512

typedef __bf16 bf16x8 __attribute__((ext_vector_type(8)));
typedef float  f32x4  __attribute__((ext_vector_type(4)));

// ---------------------------------------------------------------------------
// prep_x: x_sq[row] = ||X[row]||^2 (f32), Xb = bf16(X), out[row] = alpha
// ---------------------------------------------------------------------------
__global__ __launch_bounds__(256) void prep_x_kernel(
    const float* __restrict__ X, const float* __restrict__ alpha,
    __bf16* __restrict__ Xb, float* __restrict__ x_sq, float* __restrict__ out)
{
    int row  = blockIdx.x * 4 + (threadIdx.x >> 6);
    int lane = threadIdx.x & 63;
    const float4* src = (const float4*)(X + (size_t)row * KK) + lane * 2;
    float4 a = src[0];
    float4 b = src[1];
    float s = a.x*a.x + a.y*a.y + a.z*a.z + a.w*a.w
            + b.x*b.x + b.y*b.y + b.z*b.z + b.w*b.w;
    bf16x8 v;
    v[0]=(__bf16)a.x; v[1]=(__bf16)a.y; v[2]=(__bf16)a.z; v[3]=(__bf16)a.w;
    v[4]=(__bf16)b.x; v[5]=(__bf16)b.y; v[6]=(__bf16)b.z; v[7]=(__bf16)b.w;
    *(bf16x8*)(Xb + (size_t)row * KK + lane * 8) = v;
    #pragma unroll
    for (int o = 1; o < 64; o <<= 1) s += __shfl_xor(s, o);
    if (lane == 0) { x_sq[row] = s; out[row] = alpha[0]; }
}

// ---------------------------------------------------------------------------
// prep_zt: fused transpose+convert Z -> Zt  AND  z_sq column sums (f32)
// z_sq must be zeroed before (hipMemsetAsync in kernel_launch)
// ---------------------------------------------------------------------------
__global__ __launch_bounds__(256) void prep_zt_kernel(
    const float* __restrict__ Z, __bf16* __restrict__ Zt, float* __restrict__ z_sq)
{
    __shared__ float t[64][65];
    const int n0 = blockIdx.x * 64;   // 64 blocks
    const int k0 = blockIdx.y * 64;   // 8 blocks
    const int tid = threadIdx.x;
    const int j = tid & 63, i0 = tid >> 6;
    #pragma unroll
    for (int p = 0; p < 16; ++p) {
        int i = i0 * 16 + p;
        t[i][j] = Z[(size_t)(k0 + i) * NN + n0 + j];
    }
    __syncthreads();
    const int nl = tid >> 2, kc = tid & 3;
    bf16x8 v0, v1;
    float s = 0.0f;
    #pragma unroll
    for (int e = 0; e < 8; ++e) {
        float x = t[kc * 16 + e][nl];
        v0[e] = (__bf16)x; s += x * x;
    }
    #pragma unroll
    for (int e = 0; e < 8; ++e) {
        float x = t[kc * 16 + 8 + e][nl];
        v1[e] = (__bf16)x; s += x * x;
    }
    __bf16* dst = Zt + (size_t)(n0 + nl) * KK + k0 + kc * 16;
    *(bf16x8*)(dst)     = v0;
    *(bf16x8*)(dst + 8) = v1;
    // reduce the 4 kc-partials (lanes differ in bits 0-1) and one atomic per col
    s += __shfl_xor(s, 1);
    s += __shfl_xor(s, 2);
    if (kc == 0) atomicAdd(&z_sq[n0 + nl], s);
}

// ---------------------------------------------------------------------------
// fused bf16 GEMM 256x256 tile, BK=32, 8 waves (2M x 4N), 128x64 C per wave.
// 3-buffer LDS rotation, lookahead-2 staging, counted vmcnt(4) (T4), 2 phases
// per K-tile with setprio around MFMA cluster (T3+T5). Swizzle for 64B row
// stride: 16B-granule index ^= ((row>>1)&3), applied to BOTH the pre-swizzled
// global_load_lds source and the ds_read address (rule 21).
// ---------------------------------------------------------------------------
__global__ __launch_bounds__(512, 2) void rbfn_kernel(
    const __bf16* __restrict__ Xb, const __bf16* __restrict__ Zt,
    const float* __restrict__ x_sq, const float* __restrict__ z_sq,
    const float* __restrict__ beta, const float* __restrict__ log_gamma,
    float* __restrict__ out)
{
    __shared__ __bf16 As[3][256 * 32];   // 3 x 16KB
    __shared__ __bf16 Bs[3][256 * 32];   // 3 x 16KB

    const int tid  = threadIdx.x;
    const int wid  = tid >> 6;          // 0..7
    const int lane = tid & 63;
    const int wr   = wid >> 2;          // 0..1  (M half: 128 rows)
    const int wcn  = wid & 3;           // 0..3  (N quarter: 64 cols)
    const int row0 = blockIdx.x * 256;
    const int col0 = blockIdx.y * 256;

    // staging: lane l writes LDS granule l of a 1KB/16-row chunk.
    // stored element must be (row = l>>2, kgran = (l&3) ^ ((l>>3)&3)).
    const int srow = lane >> 2;                              // 0..15
    const int skel = (((lane & 3) ^ ((lane >> 3) & 3)) * 8); // 0/8/16/24
    // wave wid stages chunks 2*wid and 2*wid+1 of A and of B (rows wid*32..+31)
    const __bf16* Ab = Xb + (size_t)(row0 + wid * 32 + srow) * KK + skel;
    const __bf16* Bb = Zt + (size_t)(col0 + wid * 32 + srow) * KK + skel;

#define GLDS(gp, lp) __builtin_amdgcn_global_load_lds( \
        (const __attribute__((address_space(1))) void*)(gp), \
        (__attribute__((address_space(3))) void*)(lp), 16, 0, 0)
#define STAGE_A(kt, b) do { const size_t _ko = (size_t)(kt) * 32; \
        GLDS(Ab + _ko,           &As[b][wid * 1024]); \
        GLDS(Ab + 16*KK + _ko,   &As[b][wid * 1024 + 512]); } while (0)
#define STAGE_B(kt, b) do { const size_t _ko = (size_t)(kt) * 32; \
        GLDS(Bb + _ko,           &Bs[b][wid * 1024]); \
        GLDS(Bb + 16*KK + _ko,   &Bs[b][wid * 1024 + 512]); } while (0)

    f32x4 acc[8][4] = {};

    // prologue: tiles 0,1 staged; drain tile 0 (8 issued, wait to <=4)
    STAGE_A(0, 0); STAGE_B(0, 0);
    STAGE_A(1, 1); STAGE_B(1, 1);
    asm volatile("s_waitcnt vmcnt(4)" ::: "memory");
    __builtin_amdgcn_s_barrier();

    const int l15 = lane & 15;
    const int gcol = lane >> 4;          // 16B-granule column 0..3

    int cur = 0;
    #pragma unroll 1
    for (int t = 0; t < 16; ++t) {
        const int sb = (cur >= 1) ? cur - 1 : cur + 2;   // (t+2)%3
        const bool stage_ok = (t + 2 < 16);
        const char* curA = (const char*)As[cur];
        const char* curB = (const char*)Bs[cur];

        bf16x8 af[4], bfv[4];

        // ---------------- phase 0: m-frags 0..3, load B frags (cached) ----
        #pragma unroll
        for (int m = 0; m < 4; ++m) {
            const int rr = wr * 128 + m * 16 + l15;
            const int off = rr * 64 + (((gcol ^ ((rr >> 1) & 3))) << 4);
            af[m] = *(const bf16x8*)(curA + off);
        }
        #pragma unroll
        for (int n = 0; n < 4; ++n) {
            const int rb = wcn * 64 + n * 16 + l15;
            const int off = rb * 64 + (((gcol ^ ((rb >> 1) & 3))) << 4);
            bfv[n] = *(const bf16x8*)(curB + off);
        }
        if (stage_ok) STAGE_A(t + 2, sb);
        __builtin_amdgcn_s_barrier();
        asm volatile("s_waitcnt lgkmcnt(0)" ::: "memory");
        __builtin_amdgcn_sched_barrier(0);
        __builtin_amdgcn_s_setprio(1);
        #pragma unroll
        for (int m = 0; m < 4; ++m)
            #pragma unroll
            for (int n = 0; n < 4; ++n)
                acc[m][n] = __builtin_amdgcn_mfma_f32_16x16x32_bf16(
                    af[m], bfv[n], acc[m][n], 0, 0, 0);
        __builtin_amdgcn_s_setprio(0);
        __builtin_amdgcn_s_barrier();

        // ---------------- phase 1: m-frags 4..7, reuse B frags ------------
        #pragma unroll
        for (int m = 0; m < 4; ++m) {
            const int rr = wr * 128 + (m + 4) * 16 + l15;
            const int off = rr * 64 + (((gcol ^ ((rr >> 1) & 3))) << 4);
            af[m] = *(const bf16x8*)(curA + off);
        }
        if (stage_ok) STAGE_B(t + 2, sb);
        __builtin_amdgcn_s_barrier();
        asm volatile("s_waitcnt lgkmcnt(0)" ::: "memory");
        __builtin_amdgcn_sched_barrier(0);
        __builtin_amdgcn_s_setprio(1);
        #pragma unroll
        for (int m = 0; m < 4; ++m)
            #pragma unroll
            for (int n = 0; n < 4; ++n)
                acc[m + 4][n] = __builtin_amdgcn_mfma_f32_16x16x32_bf16(
                    af[m], bfv[n], acc[m + 4][n], 0, 0, 0);
        __builtin_amdgcn_s_setprio(0);

        // tile boundary: tile t+1 (staged during t-1) must be landed.
        // loads issued after it = tile t+2's 4  ->  counted vmcnt(4).
        if (t <= 13)       asm volatile("s_waitcnt vmcnt(4)" ::: "memory");
        else if (t == 14)  asm volatile("s_waitcnt vmcnt(0)" ::: "memory");
        __builtin_amdgcn_s_barrier();

        cur = (cur >= 2) ? 0 : cur + 1;
    }
#undef STAGE_A
#undef STAGE_B
#undef GLDS

    // ---- fused RBF epilogue ----------------------------------------------
    const float gamma = __expf(log_gamma[0]);
    const float c2    = gamma * 1.4426950408889634f;
    const float twoc2 = 2.0f * c2;

    float czn[4], bet[4];
    const int colb = col0 + wcn * 64 + l15;
    #pragma unroll
    for (int n = 0; n < 4; ++n) {
        const int c = colb + n * 16;
        czn[n] = -c2 * z_sq[c];
        bet[n] = beta[c];
    }

    const int rowb = row0 + wr * 128 + (lane >> 4) * 4;
    #pragma unroll
    for (int m = 0; m < 8; ++m) {
        #pragma unroll
        for (int j = 0; j < 4; ++j) {
            const int r = rowb + m * 16 + j;
            const float cx = -c2 * x_sq[r];
            float p = 0.0f;
            #pragma unroll
            for (int n = 0; n < 4; ++n) {
                const float arg = fmaf(twoc2, acc[m][n][j], cx + czn[n]);
                p = fmaf(exp2f(arg), bet[n], p);
            }
            p += __shfl_xor(p, 1);
            p += __shfl_xor(p, 2);
            p += __shfl_xor(p, 4);
            p += __shfl_xor(p, 8);
            if (l15 == 0) atomicAdd(&out[r], p);
        }
    }
}

// ---------------------------------------------------------------------------
extern "C" void kernel_launch(void* const* d_in, const int* in_sizes, int n_in,
                              void* d_out, int out_size, void* d_ws, size_t ws_size,
                              hipStream_t stream) {
    const float* X         = (const float*)d_in[0];
    const float* alpha     = (const float*)d_in[1];
    const float* log_gamma = (const float*)d_in[2];
    const float* beta      = (const float*)d_in[3];
    const float* Z         = (const float*)d_in[4];

    char* ws = (char*)d_ws;
    __bf16* Xb   = (__bf16*)(ws);                       // 16 MB
    __bf16* Zt   = (__bf16*)(ws + 16777216);            //  4 MB
    float*  x_sq = (float*) (ws + 20971520);            // 64 KB
    float*  z_sq = (float*) (ws + 21037056);            // 16 KB
    float*  out  = (float*)d_out;

    hipMemsetAsync(z_sq, 0, NN * sizeof(float), stream);
    prep_x_kernel <<<4096, 256, 0, stream>>>(X, alpha, Xb, x_sq, out);
    prep_zt_kernel<<<dim3(64, 8), 256, 0, stream>>>(Z, Zt, z_sq);
    rbfn_kernel   <<<dim3(64, 16), 512, 0, stream>>>(Xb, Zt, x_sq, z_sq, beta, log_gamma, out);
}

// Round 8
// 187.678 us; speedup vs baseline: 1.2656x; 1.1765x over previous
//
#include <hip/hip_runtime.h>
#include <hip/hip_bf16.h>

#define MM 16384
#define NN 4096
#define KK 512

typedef __bf16 bf16x8 __attribute__((ext_vector_type(8)));
typedef float  f32x4  __attribute__((ext_vector_type(4)));

// ---------------------------------------------------------------------------
// prep_x: x_sq[row] = ||X[row]||^2 (f32), Xb = bf16(X)
// ---------------------------------------------------------------------------
__global__ __launch_bounds__(256) void prep_x_kernel(
    const float* __restrict__ X,
    __bf16* __restrict__ Xb, float* __restrict__ x_sq)
{
    int row  = blockIdx.x * 4 + (threadIdx.x >> 6);
    int lane = threadIdx.x & 63;
    const float4* src = (const float4*)(X + (size_t)row * KK) + lane * 2;
    float4 a = src[0];
    float4 b = src[1];
    float s = a.x*a.x + a.y*a.y + a.z*a.z + a.w*a.w
            + b.x*b.x + b.y*b.y + b.z*b.z + b.w*b.w;
    bf16x8 v;
    v[0]=(__bf16)a.x; v[1]=(__bf16)a.y; v[2]=(__bf16)a.z; v[3]=(__bf16)a.w;
    v[4]=(__bf16)b.x; v[5]=(__bf16)b.y; v[6]=(__bf16)b.z; v[7]=(__bf16)b.w;
    *(bf16x8*)(Xb + (size_t)row * KK + lane * 8) = v;
    #pragma unroll
    for (int o = 1; o < 64; o <<= 1) s += __shfl_xor(s, o);
    if (lane == 0) x_sq[row] = s;
}

// ---------------------------------------------------------------------------
// prep_zt: transpose+convert Z -> Zt AND per-k-block z_sq partials (no atomics)
// zsq_part[by][col], by = k-block 0..7
// ---------------------------------------------------------------------------
__global__ __launch_bounds__(256) void prep_zt_kernel(
    const float* __restrict__ Z, __bf16* __restrict__ Zt,
    float* __restrict__ zsq_part)
{
    __shared__ float t[64][65];
    const int n0 = blockIdx.x * 64;   // 64 blocks
    const int k0 = blockIdx.y * 64;   // 8 blocks
    const int tid = threadIdx.x;
    const int j = tid & 63, i0 = tid >> 6;
    #pragma unroll
    for (int p = 0; p < 16; ++p) {
        int i = i0 * 16 + p;
        t[i][j] = Z[(size_t)(k0 + i) * NN + n0 + j];
    }
    __syncthreads();
    const int nl = tid >> 2, kc = tid & 3;
    bf16x8 v0, v1;
    float s = 0.0f;
    #pragma unroll
    for (int e = 0; e < 8; ++e) {
        float x = t[kc * 16 + e][nl];
        v0[e] = (__bf16)x; s += x * x;
    }
    #pragma unroll
    for (int e = 0; e < 8; ++e) {
        float x = t[kc * 16 + 8 + e][nl];
        v1[e] = (__bf16)x; s += x * x;
    }
    __bf16* dst = Zt + (size_t)(n0 + nl) * KK + k0 + kc * 16;
    *(bf16x8*)(dst)     = v0;
    *(bf16x8*)(dst + 8) = v1;
    s += __shfl_xor(s, 1);
    s += __shfl_xor(s, 2);
    if (kc == 0) zsq_part[blockIdx.y * NN + n0 + nl] = s;
}

// ---------------------------------------------------------------------------
// fused bf16 GEMM 256x256 tile, BK=32, 8 waves (2M x 4N), 128x64 C per wave.
// 3-buffer LDS rotation, lookahead-2 staging, counted vmcnt(4). Compiler-
// scheduled ds_read->MFMA (no manual lgkmcnt pins). Swizzle: 16B-granule
// index ^= ((row>>1)&3), pre-swizzled global source + swizzled ds_read.
// Epilogue: RBF + in-LDS cross-wave reduce -> deterministic partial store.
// ---------------------------------------------------------------------------
__global__ __launch_bounds__(512) void rbfn_kernel(
    const __bf16* __restrict__ Xb, const __bf16* __restrict__ Zt,
    const float* __restrict__ x_sq, const float* __restrict__ zsq_part,
    const float* __restrict__ beta, const float* __restrict__ log_gamma,
    float* __restrict__ partial)
{
    __shared__ __bf16 As[3][256 * 32];   // 3 x 16KB
    __shared__ __bf16 Bs[3][256 * 32];   // 3 x 16KB

    const int tid  = threadIdx.x;
    const int wid  = tid >> 6;          // 0..7
    const int lane = tid & 63;
    const int wr   = wid >> 2;          // 0..1  (M half: 128 rows)
    const int wcn  = wid & 3;           // 0..3  (N quarter: 64 cols)
    // XCD-bijective swizzle on x (64 tiles, 8 XCDs): XCD k gets tiles 8k..8k+7
    const int bx   = blockIdx.x;
    const int cxt  = (bx & 7) * 8 + (bx >> 3);
    const int cy   = blockIdx.y;
    const int row0 = cxt * 256;
    const int col0 = cy * 256;

    // staging: lane l writes LDS granule l of a 1KB/16-row chunk.
    // stored element must be (row = l>>2, kgran = (l&3) ^ ((l>>3)&3)).
    const int srow = lane >> 2;                              // 0..15
    const int skel = (((lane & 3) ^ ((lane >> 3) & 3)) * 8); // 0/8/16/24
    const __bf16* Ab = Xb + (size_t)(row0 + wid * 32 + srow) * KK + skel;
    const __bf16* Bb = Zt + (size_t)(col0 + wid * 32 + srow) * KK + skel;

#define GLDS(gp, lp) __builtin_amdgcn_global_load_lds( \
        (const __attribute__((address_space(1))) void*)(gp), \
        (__attribute__((address_space(3))) void*)(lp), 16, 0, 0)
#define STAGE_A(kt, b) do { const size_t _ko = (size_t)(kt) * 32; \
        GLDS(Ab + _ko,           &As[b][wid * 1024]); \
        GLDS(Ab + 16*KK + _ko,   &As[b][wid * 1024 + 512]); } while (0)
#define STAGE_B(kt, b) do { const size_t _ko = (size_t)(kt) * 32; \
        GLDS(Bb + _ko,           &Bs[b][wid * 1024]); \
        GLDS(Bb + 16*KK + _ko,   &Bs[b][wid * 1024 + 512]); } while (0)

    f32x4 acc[8][4] = {};

    // prologue: tiles 0,1 staged; drain tile 0 (8 issued, wait to <=4)
    STAGE_A(0, 0); STAGE_B(0, 0);
    STAGE_A(1, 1); STAGE_B(1, 1);
    asm volatile("s_waitcnt vmcnt(4)" ::: "memory");
    __builtin_amdgcn_s_barrier();

    const int l15 = lane & 15;
    const int gcol = lane >> 4;          // 16B-granule column 0..3

    int cur = 0;
    #pragma unroll 1
    for (int t = 0; t < 16; ++t) {
        const int sb = (cur >= 1) ? cur - 1 : cur + 2;   // (t+2)%3
        const bool stage_ok = (t + 2 < 16);
        const char* curA = (const char*)As[cur];
        const char* curB = (const char*)Bs[cur];

        bf16x8 af[4], bfv[4];

        // ---------------- phase 0: m-frags 0..3 + B frags -----------------
        #pragma unroll
        for (int m = 0; m < 4; ++m) {
            const int rr = wr * 128 + m * 16 + l15;
            const int off = rr * 64 + (((gcol ^ ((rr >> 1) & 3))) << 4);
            af[m] = *(const bf16x8*)(curA + off);
        }
        #pragma unroll
        for (int n = 0; n < 4; ++n) {
            const int rb = wcn * 64 + n * 16 + l15;
            const int off = rb * 64 + (((gcol ^ ((rb >> 1) & 3))) << 4);
            bfv[n] = *(const bf16x8*)(curB + off);
        }
        if (stage_ok) STAGE_A(t + 2, sb);
        __builtin_amdgcn_s_barrier();
        __builtin_amdgcn_s_setprio(1);
        #pragma unroll
        for (int m = 0; m < 4; ++m)
            #pragma unroll
            for (int n = 0; n < 4; ++n)
                acc[m][n] = __builtin_amdgcn_mfma_f32_16x16x32_bf16(
                    af[m], bfv[n], acc[m][n], 0, 0, 0);
        __builtin_amdgcn_s_setprio(0);
        __builtin_amdgcn_s_barrier();

        // ---------------- phase 1: m-frags 4..7, reuse B frags ------------
        #pragma unroll
        for (int m = 0; m < 4; ++m) {
            const int rr = wr * 128 + (m + 4) * 16 + l15;
            const int off = rr * 64 + (((gcol ^ ((rr >> 1) & 3))) << 4);
            af[m] = *(const bf16x8*)(curA + off);
        }
        if (stage_ok) STAGE_B(t + 2, sb);
        __builtin_amdgcn_s_barrier();
        __builtin_amdgcn_s_setprio(1);
        #pragma unroll
        for (int m = 0; m < 4; ++m)
            #pragma unroll
            for (int n = 0; n < 4; ++n)
                acc[m + 4][n] = __builtin_amdgcn_mfma_f32_16x16x32_bf16(
                    af[m], bfv[n], acc[m + 4][n], 0, 0, 0);
        __builtin_amdgcn_s_setprio(0);

        // tile boundary: tile t+1's loads landed when vmcnt<=4 (t+2 in flight)
        if (t <= 13)       asm volatile("s_waitcnt vmcnt(4)" ::: "memory");
        else if (t == 14)  asm volatile("s_waitcnt vmcnt(0)" ::: "memory");
        __builtin_amdgcn_s_barrier();

        cur = (cur >= 2) ? 0 : cur + 1;
    }
#undef STAGE_A
#undef STAGE_B
#undef GLDS

    // ---- fused RBF epilogue (no global atomics) --------------------------
    const float gamma = __expf(log_gamma[0]);
    const float c2    = gamma * 1.4426950408889634f;
    const float twoc2 = 2.0f * c2;

    float czn[4], bet[4];
    const int colb = col0 + wcn * 64 + l15;
    #pragma unroll
    for (int n = 0; n < 4; ++n) {
        const int c = colb + n * 16;
        float zs = 0.0f;
        #pragma unroll
        for (int q = 0; q < 8; ++q) zs += zsq_part[q * NN + c];
        czn[n] = -c2 * zs;
        bet[n] = beta[c];
    }

    // per-wave 64-col sums -> LDS -> cross-wcn reduce -> partial[cy][row]
    float* red = (float*)&As[0][0];      // [2 wr][4 wcn][128 rows] = 4KB
    const int g4 = lane >> 4;
    #pragma unroll
    for (int m = 0; m < 8; ++m) {
        #pragma unroll
        for (int j = 0; j < 4; ++j) {
            const int rloc = m * 16 + g4 * 4 + j;          // 0..127
            const float cx = -c2 * x_sq[row0 + wr * 128 + rloc];
            float p = 0.0f;
            #pragma unroll
            for (int n = 0; n < 4; ++n) {
                const float arg = fmaf(twoc2, acc[m][n][j], cx + czn[n]);
                p = fmaf(exp2f(arg), bet[n], p);
            }
            p += __shfl_xor(p, 1);
            p += __shfl_xor(p, 2);
            p += __shfl_xor(p, 4);
            p += __shfl_xor(p, 8);
            if (l15 == 0) red[(wr * 4 + wcn) * 128 + rloc] = p;
        }
    }
    __syncthreads();
    if (tid < 256) {
        const int w = tid >> 7, rloc = tid & 127;
        float s = red[(w * 4 + 0) * 128 + rloc] + red[(w * 4 + 1) * 128 + rloc]
                + red[(w * 4 + 2) * 128 + rloc] + red[(w * 4 + 3) * 128 + rloc];
        partial[(size_t)cy * MM + row0 + tid] = s;
    }
}

// ---------------------------------------------------------------------------
// reduce: out[r] = alpha + sum_{cy} partial[cy][r]
// ---------------------------------------------------------------------------
__global__ __launch_bounds__(256) void reduce_kernel(
    const float* __restrict__ partial, const float* __restrict__ alpha,
    float* __restrict__ out)
{
    const int r = blockIdx.x * 256 + threadIdx.x;
    float s = alpha[0];
    #pragma unroll
    for (int q = 0; q < 16; ++q) s += partial[(size_t)q * MM + r];
    out[r] = s;
}

// ---------------------------------------------------------------------------
extern "C" void kernel_launch(void* const* d_in, const int* in_sizes, int n_in,
                              void* d_out, int out_size, void* d_ws, size_t ws_size,
                              hipStream_t stream) {
    const float* X         = (const float*)d_in[0];
    const float* alpha     = (const float*)d_in[1];
    const float* log_gamma = (const float*)d_in[2];
    const float* beta      = (const float*)d_in[3];
    const float* Z         = (const float*)d_in[4];

    char* ws = (char*)d_ws;
    __bf16* Xb       = (__bf16*)(ws);                   // 16 MB
    __bf16* Zt       = (__bf16*)(ws + 16777216);        //  4 MB
    float*  x_sq     = (float*) (ws + 20971520);        // 64 KB
    float*  zsq_part = (float*) (ws + 21037056);        // 128 KB (8 x 4096)
    float*  partial  = (float*) (ws + 21168128);        // 1 MB  (16 x 16384)
    float*  out      = (float*)d_out;

    prep_x_kernel <<<4096, 256, 0, stream>>>(X, Xb, x_sq);
    prep_zt_kernel<<<dim3(64, 8), 256, 0, stream>>>(Z, Zt, zsq_part);
    rbfn_kernel   <<<dim3(64, 16), 512, 0, stream>>>(Xb, Zt, x_sq, zsq_part,
                                                     beta, log_gamma, partial);
    reduce_kernel <<<64, 256, 0, stream>>>(partial, alpha, out);
}

// Round 10
// 186.004 us; speedup vs baseline: 1.2770x; 1.0090x over previous
//
#include <hip/hip_runtime.h>
#include <hip/hip_bf16.h>

#define MM 16384
#define NN 4096
#define KK 512

typedef __bf16 bf16x8 __attribute__((ext_vector_type(8)));
typedef float  f32x4  __attribute__((ext_vector_type(4)));

// ---------------------------------------------------------------------------
// prep_x: x_sq[row] = ||X[row]||^2 (f32), Xb = bf16(X)
// ---------------------------------------------------------------------------
__global__ __launch_bounds__(256) void prep_x_kernel(
    const float* __restrict__ X,
    __bf16* __restrict__ Xb, float* __restrict__ x_sq)
{
    int row  = blockIdx.x * 4 + (threadIdx.x >> 6);
    int lane = threadIdx.x & 63;
    const float4* src = (const float4*)(X + (size_t)row * KK) + lane * 2;
    float4 a = src[0];
    float4 b = src[1];
    float s = a.x*a.x + a.y*a.y + a.z*a.z + a.w*a.w
            + b.x*b.x + b.y*b.y + b.z*b.z + b.w*b.w;
    bf16x8 v;
    v[0]=(__bf16)a.x; v[1]=(__bf16)a.y; v[2]=(__bf16)a.z; v[3]=(__bf16)a.w;
    v[4]=(__bf16)b.x; v[5]=(__bf16)b.y; v[6]=(__bf16)b.z; v[7]=(__bf16)b.w;
    *(bf16x8*)(Xb + (size_t)row * KK + lane * 8) = v;
    #pragma unroll
    for (int o = 1; o < 64; o <<= 1) s += __shfl_xor(s, o);
    if (lane == 0) x_sq[row] = s;
}

// ---------------------------------------------------------------------------
// prep_zt: transpose+convert Z -> Zt AND per-k-block z_sq partials (no atomics)
// ---------------------------------------------------------------------------
__global__ __launch_bounds__(256) void prep_zt_kernel(
    const float* __restrict__ Z, __bf16* __restrict__ Zt,
    float* __restrict__ zsq_part)
{
    __shared__ float t[64][65];
    const int n0 = blockIdx.x * 64;   // 64 blocks
    const int k0 = blockIdx.y * 64;   // 8 blocks
    const int tid = threadIdx.x;
    const int j = tid & 63, i0 = tid >> 6;
    #pragma unroll
    for (int p = 0; p < 16; ++p) {
        int i = i0 * 16 + p;
        t[i][j] = Z[(size_t)(k0 + i) * NN + n0 + j];
    }
    __syncthreads();
    const int nl = tid >> 2, kc = tid & 3;
    bf16x8 v0, v1;
    float s = 0.0f;
    #pragma unroll
    for (int e = 0; e < 8; ++e) {
        float x = t[kc * 16 + e][nl];
        v0[e] = (__bf16)x; s += x * x;
    }
    #pragma unroll
    for (int e = 0; e < 8; ++e) {
        float x = t[kc * 16 + 8 + e][nl];
        v1[e] = (__bf16)x; s += x * x;
    }
    __bf16* dst = Zt + (size_t)(n0 + nl) * KK + k0 + kc * 16;
    *(bf16x8*)(dst)     = v0;
    *(bf16x8*)(dst + 8) = v1;
    s += __shfl_xor(s, 1);
    s += __shfl_xor(s, 2);
    if (kc == 0) zsq_part[blockIdx.y * NN + n0 + nl] = s;
}

// ---------------------------------------------------------------------------
// fused bf16 GEMM 256x256 tile, BK=32, 8 waves (2M x 4N), 128x64 C per wave.
// 3-buffer LDS rotation, lookahead-2 staging, counted vmcnt(4).
// ONE barrier per K-tile: within a tile all ds_reads/MFMAs hit the same
// stable buffer (read-read, no hazard) -- the compiler's fine-grained
// lgkmcnt scheduling overlaps reads with MFMA (m97 pattern). Swizzle:
// 16B-granule index ^= ((row>>1)&3), both sides (rule 21).
// ---------------------------------------------------------------------------
__global__ __launch_bounds__(512) void rbfn_kernel(
    const __bf16* __restrict__ Xb, const __bf16* __restrict__ Zt,
    const float* __restrict__ x_sq, const float* __restrict__ zsq_part,
    const float* __restrict__ beta, const float* __restrict__ log_gamma,
    float* __restrict__ partial)
{
    __shared__ __bf16 As[3][256 * 32];   // 3 x 16KB
    __shared__ __bf16 Bs[3][256 * 32];   // 3 x 16KB

    const int tid  = threadIdx.x;
    const int wid  = tid >> 6;          // 0..7
    const int lane = tid & 63;
    const int wr   = wid >> 2;          // 0..1  (M half: 128 rows)
    const int wcn  = wid & 3;           // 0..3  (N quarter: 64 cols)
    // XCD-bijective swizzle on x (64 tiles, 8 XCDs)
    const int bx   = blockIdx.x;
    const int cxt  = (bx & 7) * 8 + (bx >> 3);
    const int cy   = blockIdx.y;
    const int row0 = cxt * 256;
    const int col0 = cy * 256;

    const int srow = lane >> 2;                              // 0..15
    const int skel = (((lane & 3) ^ ((lane >> 3) & 3)) * 8); // 0/8/16/24
    const __bf16* Ab = Xb + (size_t)(row0 + wid * 32 + srow) * KK + skel;
    const __bf16* Bb = Zt + (size_t)(col0 + wid * 32 + srow) * KK + skel;

#define GLDS(gp, lp) __builtin_amdgcn_global_load_lds( \
        (const __attribute__((address_space(1))) void*)(gp), \
        (__attribute__((address_space(3))) void*)(lp), 16, 0, 0)
#define STAGE_A(kt, b) do { const size_t _ko = (size_t)(kt) * 32; \
        GLDS(Ab + _ko,           &As[b][wid * 1024]); \
        GLDS(Ab + 16*KK + _ko,   &As[b][wid * 1024 + 512]); } while (0)
#define STAGE_B(kt, b) do { const size_t _ko = (size_t)(kt) * 32; \
        GLDS(Bb + _ko,           &Bs[b][wid * 1024]); \
        GLDS(Bb + 16*KK + _ko,   &Bs[b][wid * 1024 + 512]); } while (0)

    f32x4 acc[8][4] = {};

    // prologue: tiles 0,1 staged; drain tile 0 (8 issued, wait to <=4)
    STAGE_A(0, 0); STAGE_B(0, 0);
    STAGE_A(1, 1); STAGE_B(1, 1);
    asm volatile("s_waitcnt vmcnt(4)" ::: "memory");
    __builtin_amdgcn_s_barrier();

    const int l15 = lane & 15;
    const int gcol = lane >> 4;          // 16B-granule column 0..3

    int cur = 0;
    #pragma unroll 1
    for (int t = 0; t < 16; ++t) {
        const int sb = (cur >= 1) ? cur - 1 : cur + 2;   // (t+2)%3
        const bool stage_ok = (t + 2 < 16);
        const char* curA = (const char*)As[cur];
        const char* curB = (const char*)Bs[cur];

        bf16x8 af[4], bfv[4];

        // reads for quadrant 0 + all B frags; stage A of tile t+2
        #pragma unroll
        for (int m = 0; m < 4; ++m) {
            const int rr = wr * 128 + m * 16 + l15;
            const int off = rr * 64 + (((gcol ^ ((rr >> 1) & 3))) << 4);
            af[m] = *(const bf16x8*)(curA + off);
        }
        #pragma unroll
        for (int n = 0; n < 4; ++n) {
            const int rb = wcn * 64 + n * 16 + l15;
            const int off = rb * 64 + (((gcol ^ ((rb >> 1) & 3))) << 4);
            bfv[n] = *(const bf16x8*)(curB + off);
        }
        if (stage_ok) STAGE_A(t + 2, sb);
        __builtin_amdgcn_s_setprio(1);
        #pragma unroll
        for (int m = 0; m < 4; ++m)
            #pragma unroll
            for (int n = 0; n < 4; ++n)
                acc[m][n] = __builtin_amdgcn_mfma_f32_16x16x32_bf16(
                    af[m], bfv[n], acc[m][n], 0, 0, 0);
        __builtin_amdgcn_s_setprio(0);

        // reads for quadrant 1 (reuse B frags); stage B of tile t+2
        #pragma unroll
        for (int m = 0; m < 4; ++m) {
            const int rr = wr * 128 + (m + 4) * 16 + l15;
            const int off = rr * 64 + (((gcol ^ ((rr >> 1) & 3))) << 4);
            af[m] = *(const bf16x8*)(curA + off);
        }
        if (stage_ok) STAGE_B(t + 2, sb);
        __builtin_amdgcn_s_setprio(1);
        #pragma unroll
        for (int m = 0; m < 4; ++m)
            #pragma unroll
            for (int n = 0; n < 4; ++n)
                acc[m + 4][n] = __builtin_amdgcn_mfma_f32_16x16x32_bf16(
                    af[m], bfv[n], acc[m + 4][n], 0, 0, 0);
        __builtin_amdgcn_s_setprio(0);

        // ONE barrier per K-tile: tile t+1 landed when vmcnt<=4 (t+2 in flight)
        if (t <= 13)       asm volatile("s_waitcnt vmcnt(4)" ::: "memory");
        else if (t == 14)  asm volatile("s_waitcnt vmcnt(0)" ::: "memory");
        __builtin_amdgcn_s_barrier();

        cur = (cur >= 2) ? 0 : cur + 1;
    }
#undef STAGE_A
#undef STAGE_B
#undef GLDS

    // ---- fused RBF epilogue (no global atomics) --------------------------
    const float gamma = __expf(log_gamma[0]);
    const float c2    = gamma * 1.4426950408889634f;
    const float twoc2 = 2.0f * c2;

    float czn[4], bet[4];
    const int colb = col0 + wcn * 64 + l15;
    #pragma unroll
    for (int n = 0; n < 4; ++n) {
        const int c = colb + n * 16;
        float zs = 0.0f;
        #pragma unroll
        for (int q = 0; q < 8; ++q) zs += zsq_part[q * NN + c];
        czn[n] = -c2 * zs;
        bet[n] = beta[c];
    }

    float* red = (float*)&As[0][0];      // [2 wr][4 wcn][128 rows] = 4KB
    const int g4 = lane >> 4;
    #pragma unroll
    for (int m = 0; m < 8; ++m) {
        #pragma unroll
        for (int j = 0; j < 4; ++j) {
            const int rloc = m * 16 + g4 * 4 + j;          // 0..127
            const float cx = -c2 * x_sq[row0 + wr * 128 + rloc];
            float p = 0.0f;
            #pragma unroll
            for (int n = 0; n < 4; ++n) {
                const float arg = fmaf(twoc2, acc[m][n][j], cx + czn[n]);
                p = fmaf(exp2f(arg), bet[n], p);
            }
            p += __shfl_xor(p, 1);
            p += __shfl_xor(p, 2);
            p += __shfl_xor(p, 4);
            p += __shfl_xor(p, 8);
            if (l15 == 0) red[(wr * 4 + wcn) * 128 + rloc] = p;
        }
    }
    __syncthreads();
    if (tid < 256) {
        const int w = tid >> 7, rloc = tid & 127;
        float s = red[(w * 4 + 0) * 128 + rloc] + red[(w * 4 + 1) * 128 + rloc]
                + red[(w * 4 + 2) * 128 + rloc] + red[(w * 4 + 3) * 128 + rloc];
        partial[(size_t)cy * MM + row0 + tid] = s;
    }
}

// ---------------------------------------------------------------------------
// reduce: out[r] = alpha + sum_{cy} partial[cy][r]
// ---------------------------------------------------------------------------
__global__ __launch_bounds__(256) void reduce_kernel(
    const float* __restrict__ partial, const float* __restrict__ alpha,
    float* __restrict__ out)
{
    const int r = blockIdx.x * 256 + threadIdx.x;
    float s = alpha[0];
    #pragma unroll
    for (int q = 0; q < 16; ++q) s += partial[(size_t)q * MM + r];
    out[r] = s;
}

// ---------------------------------------------------------------------------
extern "C" void kernel_launch(void* const* d_in, const int* in_sizes, int n_in,
                              void* d_out, int out_size, void* d_ws, size_t ws_size,
                              hipStream_t stream) {
    const float* X         = (const float*)d_in[0];
    const float* alpha     = (const float*)d_in[1];
    const float* log_gamma = (const float*)d_in[2];
    const float* beta      = (const float*)d_in[3];
    const float* Z         = (const float*)d_in[4];

    char* ws = (char*)d_ws;
    __bf16* Xb       = (__bf16*)(ws);                   // 16 MB
    __bf16* Zt       = (__bf16*)(ws + 16777216);        //  4 MB
    float*  x_sq     = (float*) (ws + 20971520);        // 64 KB
    float*  zsq_part = (float*) (ws + 21037056);        // 128 KB (8 x 4096)
    float*  partial  = (float*) (ws + 21168128);        // 1 MB  (16 x 16384)
    float*  out      = (float*)d_out;

    prep_x_kernel <<<4096, 256, 0, stream>>>(X, Xb, x_sq);
    prep_zt_kernel<<<dim3(64, 8), 256, 0, stream>>>(Z, Zt, zsq_part);
    rbfn_kernel   <<<dim3(64, 16), 512, 0, stream>>>(Xb, Zt, x_sq, zsq_part,
                                                     beta, log_gamma, partial);
    reduce_kernel <<<64, 256, 0, stream>>>(partial, alpha, out);
}